// Round 3
// baseline (688.756 us; speedup 1.0000x reference)
//
#include <hip/hip_runtime.h>
#include <math.h>

#define B_ 256
#define S_ 6
#define C_ 80
#define F_ 2048
#define E_ 300
#define H_ 1024
#define EPS_ 1e-7f
#define DEPS_ 1e-8f
#define LEAK_ 0.2f

// ---- ws layout (float offsets) ----
#define IMG_OFF   0u          // img_feats [256,2048]            = 524288
#define Z_OFF     524288u     // Z = inp@W1 [80,1024]            = 81920
#define COMAT_OFF 606208u     // comat normalized [6,80,80]      = 38400
#define ADJA_OFF  644608u     // adjA [6,80,80]                  = 38400
#define G2_OFF    683008u     // G2 = adjA@LReLU(adjA@Z) [6,80,1024]
#define PART_OFF  1174528u    // u partials [16][256,1024]       = 4194304
#define IDS_OFF   5368832u    // ids [256] (int)
#define MP_OFF    5369088u    // mean_p accum [6]
#define SEN_OFF   5369094u    // sample entropy accum [1]

// ---- d_out layout (float offsets) ----
#define OUT0_OFF 0            // output [256,80]
#define PROB_OFF 20480        // scene_probs [256,6]
#define SEN_OUT  22016        // sample_en
#define BEN_OUT  22017        // batch_en
#define CMTS_OFF 22018        // comats [256,80,80]

// K1: global max over 14x14=196 floats per (b,f) pair.
// Block = 16 pairs = 784 contiguous float4 (12.5 KB), fully-coalesced
// 100%-active reads; per-pair reduce via LDS. Pure HBM stream.
__global__ __launch_bounds__(256) void k_maxpool(const float* __restrict__ x,
                                                 float* __restrict__ img) {
    __shared__ float m1[784];
    __shared__ float m2[16][17];
    int tid = threadIdx.x;
    const float4* base = (const float4*)x + (size_t)blockIdx.x * 784;
    for (int i = tid; i < 784; i += 256) {
        float4 v = base[i];
        m1[i] = fmaxf(fmaxf(v.x, v.y), fmaxf(v.z, v.w));
    }
    __syncthreads();
    int p = tid >> 4, i = tid & 15;
    int o = p * 49 + i;
    float a = fmaxf(m1[o], fmaxf(m1[o + 16], m1[o + 32]));
    if (i == 0) a = fmaxf(a, m1[p * 49 + 48]);
    m2[p][i] = a;
    __syncthreads();
    if (tid < 16) {
        float r = m2[tid][0];
#pragma unroll
        for (int j = 1; j < 16; j++) r = fmaxf(r, m2[tid][j]);
        img[blockIdx.x * 16 + tid] = r;
    }
}

// K2: scene_scores = img @ W_scene, softmax, argmax ids, entropy accumulators.
__global__ __launch_bounds__(256) void k_scene(const float* __restrict__ img,
                                               const float* __restrict__ Ws,
                                               float* __restrict__ probs_out,
                                               int* __restrict__ ids,
                                               float* __restrict__ mp,
                                               float* __restrict__ sen) {
    __shared__ float red[6][256];
    int b = blockIdx.x, tid = threadIdx.x;
    float acc[6] = {0, 0, 0, 0, 0, 0};
#pragma unroll
    for (int i = 0; i < 8; i++) {
        int f = tid + i * 256;
        float a = img[b * F_ + f];
#pragma unroll
        for (int s = 0; s < 6; s++) acc[s] += a * Ws[f * 6 + s];
    }
    for (int s = 0; s < 6; s++) red[s][tid] = acc[s];
    __syncthreads();
    for (int off = 128; off > 0; off >>= 1) {
        if (tid < off)
            for (int s = 0; s < 6; s++) red[s][tid] += red[s][tid + off];
        __syncthreads();
    }
    if (tid == 0) {
        float sc[6], mx = -INFINITY;
        for (int s = 0; s < 6; s++) { sc[s] = red[s][0]; mx = fmaxf(mx, sc[s]); }
        float sum = 0.f;
        for (int s = 0; s < 6; s++) { sc[s] = expf(sc[s] - mx); sum += sc[s]; }
        float inv = 1.0f / sum;
        float p[6], ent = 0.f;
        int best = 0; float bv = -1.f;
        for (int s = 0; s < 6; s++) {
            p[s] = sc[s] * inv;
            probs_out[b * 6 + s] = p[s];
            ent -= p[s] * logf(p[s] + EPS_);
            if (p[s] > bv) { bv = p[s]; best = s; }
            atomicAdd(&mp[s], p[s]);
        }
        atomicAdd(sen, ent);
        ids[b] = best;
    }
}

// K3: per-scene comatrix scatter-add (popcount of ballot bitmasks),
// row-normalize by diag (diag:=1), adjA = D^-1/2 A^T D^-1/2.
// Block 0 / tid 0 also finalizes the entropy scalars (mp/sen ready).
__global__ __launch_bounds__(256) void k_comat(const float* __restrict__ y,
                                               const float* __restrict__ cm_in,
                                               const int* __restrict__ ids,
                                               const float* __restrict__ mp,
                                               const float* __restrict__ sen,
                                               float* __restrict__ comat,
                                               float* __restrict__ adjA,
                                               float* __restrict__ o_sen,
                                               float* __restrict__ o_ben) {
    int s = blockIdx.x, tid = threadIdx.x;
    if (s == 0 && tid == 0) {
        *o_sen = *sen / 256.0f;
        float ent = 0.f;
        for (int q = 0; q < 6; q++) {
            float v = mp[q] / 256.0f;
            ent -= v * logf(v + EPS_);
        }
        float invS = 1.0f / 6.0f;
        float men = -6.0f * (invS * logf(invS + EPS_));
        *o_ben = (men - ent) * 100.0f;
    }
    __shared__ unsigned long long colq[80][4];
    __shared__ float cm[6400];
    __shared__ float diag[80], Dn[80];
    __shared__ int idsL[256];
    idsL[tid] = ids[tid];
    __syncthreads();
    int wave = tid >> 6, lane = tid & 63;
    bool ok = (idsL[tid] == s);
    for (int i = 0; i < 80; i++) {
        bool pred = ok && (y[tid * 80 + i] != 0.0f);
        unsigned long long mk = __ballot(pred);
        if (lane == 0) colq[i][wave] = mk;
    }
    __syncthreads();
    for (int p = tid; p < 6400; p += 256) {
        int i = p / 80, j = p - i * 80;
        int cnt = 0;
#pragma unroll
        for (int w = 0; w < 4; w++) cnt += __popcll(colq[i][w] & colq[j][w]);
        cm[p] = cm_in[s * 6400 + p] + (float)cnt;
    }
    __syncthreads();
    if (tid < 80) diag[tid] = cm[tid * 81];
    __syncthreads();
    for (int p = tid; p < 6400; p += 256) {
        int i = p / 80, j = p - i * 80;
        float v = (i == j) ? 1.0f : cm[p] / (diag[i] + DEPS_);
        cm[p] = v;
        comat[s * 6400 + p] = v;
    }
    __syncthreads();
    if (tid < 80) {
        float rs = 0.f;
        for (int j = 0; j < 80; j++) rs += cm[tid * 80 + j];
        Dn[tid] = 1.0f / sqrtf(rs);
    }
    __syncthreads();
    for (int p = tid; p < 6400; p += 256) {
        int i = p / 80, j = p - i * 80;
        adjA[s * 6400 + p] = Dn[i] * cm[j * 80 + i] * Dn[j];
    }
}

// K4: Z = inp @ W1  [80,300]@[300,1024]
__global__ __launch_bounds__(256) void k_z(const float* __restrict__ inp,
                                           const float* __restrict__ W1,
                                           float* __restrict__ Z) {
    int c = blockIdx.x >> 2;
    int h = ((blockIdx.x & 3) << 8) + threadIdx.x;
    float acc = 0.f;
    for (int e = 0; e < E_; e++) acc += inp[c * E_ + e] * W1[e * H_ + h];
    Z[c * H_ + h] = acc;
}

// K5 (fused g+g2): per (s, 64-col chunk): stage adjA[s] + Z-chunk in LDS,
// g = LReLU(adjA@Zc) in LDS (never touches HBM), G2 = adjA@g to global.
__global__ __launch_bounds__(256) void k_gg2(const float* __restrict__ adjA,
                                             const float* __restrict__ Z,
                                             float* __restrict__ G2) {
    __shared__ float aL[6400];
    __shared__ float zL[80 * 64];
    __shared__ float gL[80 * 64];
    int s = blockIdx.x >> 4;
    int c0 = (blockIdx.x & 15) << 6;
    int tid = threadIdx.x;
    int c = tid & 63, r4 = tid >> 6;
    for (int p = tid; p < 6400; p += 256) aL[p] = adjA[s * 6400 + p];
    for (int j = r4; j < 80; j += 4) zL[j * 64 + c] = Z[j * 1024 + c0 + c];
    __syncthreads();
    for (int pass = 0; pass < 20; pass++) {
        int r = pass * 4 + r4;
        float acc = 0.f;
#pragma unroll 8
        for (int j = 0; j < 80; j++) acc += aL[r * 80 + j] * zL[j * 64 + c];
        gL[r * 64 + c] = acc > 0.f ? acc : LEAK_ * acc;
    }
    __syncthreads();
    for (int pass = 0; pass < 20; pass++) {
        int r = pass * 4 + r4;
        float acc = 0.f;
#pragma unroll 8
        for (int j = 0; j < 80; j++) acc += aL[r * 80 + j] * gL[j * 64 + c];
        G2[(size_t)(s * 80 + r) * 1024 + c0 + c] = acc;
    }
}

// K6: u = img_feats @ W2^T, split-K=16, 64x128 tile (2 blocks/CU), 4x8 acc.
__global__ __launch_bounds__(256) void k_ugemm(const float* __restrict__ A,
                                               const float* __restrict__ Bm,
                                               float* __restrict__ part) {
    __shared__ float As[16 * 68];
    __shared__ float Bs[16 * 132];
    int tid = threadIdx.x;
    int m0 = blockIdx.y * 64, h0 = blockIdx.x * 128;
    int kbase = blockIdx.z * 128;
    float acc[4][8];
#pragma unroll
    for (int i = 0; i < 4; i++)
#pragma unroll
        for (int j = 0; j < 8; j++) acc[i][j] = 0.f;
    int r0 = (tid >> 4) << 2, c0 = (tid & 15) << 3;
    for (int st = 0; st < 8; st++) {
        int kc = kbase + st * 16;
        {
            int r = tid >> 2, kq = tid & 3;
            float4 av = *(const float4*)(A + (size_t)(m0 + r) * 2048 + kc + (kq << 2));
            int kk = kq << 2;
            As[(kk + 0) * 68 + r] = av.x; As[(kk + 1) * 68 + r] = av.y;
            As[(kk + 2) * 68 + r] = av.z; As[(kk + 3) * 68 + r] = av.w;
        }
#pragma unroll
        for (int l = 0; l < 2; l++) {
            int fid = tid + (l << 8);
            int r = fid >> 2, kq = fid & 3;
            float4 bv = *(const float4*)(Bm + (size_t)(h0 + r) * 2048 + kc + (kq << 2));
            int kk = kq << 2;
            Bs[(kk + 0) * 132 + r] = bv.x; Bs[(kk + 1) * 132 + r] = bv.y;
            Bs[(kk + 2) * 132 + r] = bv.z; Bs[(kk + 3) * 132 + r] = bv.w;
        }
        __syncthreads();
#pragma unroll
        for (int k = 0; k < 16; k++) {
            float4 a0 = *(const float4*)&As[k * 68 + r0];
            float4 b0 = *(const float4*)&Bs[k * 132 + c0];
            float4 b1 = *(const float4*)&Bs[k * 132 + c0 + 4];
            float ar[4] = {a0.x, a0.y, a0.z, a0.w};
            float br[8] = {b0.x, b0.y, b0.z, b0.w, b1.x, b1.y, b1.z, b1.w};
#pragma unroll
            for (int i = 0; i < 4; i++)
#pragma unroll
                for (int j = 0; j < 8; j++) acc[i][j] += ar[i] * br[j];
        }
        __syncthreads();
    }
    float* pu = part + (size_t)blockIdx.z * 262144;
#pragma unroll
    for (int i = 0; i < 4; i++) {
        int row = m0 + r0 + i;
        float4 v0 = {acc[i][0], acc[i][1], acc[i][2], acc[i][3]};
        float4 v1 = {acc[i][4], acc[i][5], acc[i][6], acc[i][7]};
        *(float4*)(pu + (size_t)row * 1024 + h0 + c0) = v0;
        *(float4*)(pu + (size_t)row * 1024 + h0 + c0 + 4) = v1;
    }
}

// K7 (fused out+gather): u[b] = sum split-K partials; out[b,c] = G2[s,c,:]·u;
// then copy comat[s] -> comats[b].
__global__ __launch_bounds__(256) void k_out(const float* __restrict__ part,
                                             const float* __restrict__ G2,
                                             const float* __restrict__ comat,
                                             const int* __restrict__ ids,
                                             float* __restrict__ out0,
                                             float* __restrict__ cmts) {
    __shared__ float ul[1024];
    int b = blockIdx.x, tid = threadIdx.x;
    int s = ids[b];
    for (int h = tid; h < 1024; h += 256) {
        float a = 0.f;
#pragma unroll
        for (int z = 0; z < 16; z++) a += part[z * 262144 + b * 1024 + h];
        ul[h] = a;
    }
    __syncthreads();
    int wave = tid >> 6, lane = tid & 63;
    const float4* u4 = (const float4*)ul;
    for (int c = wave; c < 80; c += 4) {
        const float4* row = (const float4*)(G2 + (size_t)(s * 80 + c) * 1024);
        float a = 0.f;
#pragma unroll
        for (int t = 0; t < 4; t++) {
            float4 gv = row[lane + t * 64];
            float4 uv = u4[lane + t * 64];
            a += gv.x * uv.x + gv.y * uv.y + gv.z * uv.z + gv.w * uv.w;
        }
#pragma unroll
        for (int off = 32; off >= 1; off >>= 1) a += __shfl_xor(a, off);
        if (lane == 0) out0[b * 80 + c] = a;
    }
    const float4* src = (const float4*)(comat + s * 6400);
    float4* dst = (float4*)(cmts + (size_t)b * 6400);
    for (int i = tid; i < 1600; i += 256) dst[i] = src[i];
}

extern "C" void kernel_launch(void* const* d_in, const int* in_sizes, int n_in,
                              void* d_out, int out_size, void* d_ws, size_t ws_size,
                              hipStream_t stream) {
    const float* x    = (const float*)d_in[0];
    const float* inp  = (const float*)d_in[1];
    const float* y    = (const float*)d_in[2];
    const float* cmin = (const float*)d_in[3];
    const float* Ws   = (const float*)d_in[4];
    const float* W1   = (const float*)d_in[5];
    const float* W2   = (const float*)d_in[6];
    float* out = (float*)d_out;
    float* W = (float*)d_ws;

    float* img   = W + IMG_OFF;
    float* Z     = W + Z_OFF;
    float* comat = W + COMAT_OFF;
    float* adjA  = W + ADJA_OFF;
    float* G2    = W + G2_OFF;
    float* part  = W + PART_OFF;
    int*   ids   = (int*)(W + IDS_OFF);
    float* mp    = W + MP_OFF;
    float* sen   = W + SEN_OFF;

    hipMemsetAsync(mp, 0, 7 * sizeof(float), stream);
    k_maxpool<<<32768, 256, 0, stream>>>(x, img);
    k_scene<<<256, 256, 0, stream>>>(img, Ws, out + PROB_OFF, ids, mp, sen);
    k_comat<<<6, 256, 0, stream>>>(y, cmin, ids, mp, sen, comat, adjA,
                                   out + SEN_OUT, out + BEN_OUT);
    k_z<<<320, 256, 0, stream>>>(inp, W1, Z);
    k_gg2<<<96, 256, 0, stream>>>(adjA, Z, G2);
    k_ugemm<<<dim3(8, 4, 16), 256, 0, stream>>>(img, W2, part);
    k_out<<<256, 256, 0, stream>>>(part, G2, comat, ids,
                                   out + OUT0_OFF, out + CMTS_OFF);
}